// Round 12
// baseline (1107.967 us; speedup 1.0000x reference)
//
#include <hip/hip_runtime.h>
#include <stdint.h>

typedef short bf16x8 __attribute__((ext_vector_type(8)));
typedef float f32x4 __attribute__((ext_vector_type(4)));

#define NROWS 8192
#define DIM   128
#define ZSCALE 3.7982824f
#define LN2F  0.6931471805599453f

// zf layout (fragment-linear): chunk (b, ks) = 1KB at (b*4+ks)*1024 bytes;
// lane l (g=l>>4, q=l&15) holds z[b*16+q][ks*32+g*8 .. +8] as bf16x8.

__device__ __forceinline__ unsigned short f32_to_bf16_bits(float x) {
  union { float f; uint32_t u; } v; v.f = x;
  uint32_t r = v.u + 0x7FFFu + ((v.u >> 16) & 1u);  // RNE
  return (unsigned short)(r >> 16);
}

template <typename T>
__device__ __forceinline__ T* opq(T* p) {
  asm volatile("" : "+v"(p));
  return p;
}
__device__ __forceinline__ void sinkb(const bf16x8& v) {  // keeps load alive
  asm volatile("" ::"v"((int)v[0]));
}
__device__ __forceinline__ void sinkf(float v) { asm volatile("" ::"v"(v)); }

// K0: Wtf = W in B-fragment order; zero sumexp/topacc.
__global__ __launch_bounds__(256) void k_wprep(const float* __restrict__ W,
                                               unsigned short* __restrict__ Wtf,
                                               float* __restrict__ sumexp,
                                               float* __restrict__ topacc) {
  const int idx = blockIdx.x * 256 + threadIdx.x;
  if (idx < 2048) {
    const int l = idx & 63, chunk = idx >> 6;
    const int tj = chunk >> 2, ks = chunk & 3, g = l >> 4, q = l & 15;
    const float* wp = W + (size_t)(ks * 32 + g * 8) * DIM + tj * 16 + q;
    bf16x8 o;
#pragma unroll
    for (int e = 0; e < 8; ++e) o[e] = (short)f32_to_bf16_bits(wp[(size_t)e * DIM]);
    *(bf16x8*)(Wtf + (size_t)idx * 8) = o;
  }
  if (idx < NROWS) sumexp[idx] = 0.f;
  if (idx == 0) topacc[0] = 0.f;
}

// K1: zf = fragment-order bf16( ZSCALE * normalize(anchor @ W + bias) ).
__global__ __launch_bounds__(256) void k_proj_norm(
    const float* __restrict__ anchor, const unsigned short* __restrict__ Wtf,
    const float* __restrict__ bias, unsigned short* __restrict__ zf) {
  __shared__ float part[4][16][132];
  const int t = threadIdx.x;
  const int wv = t >> 6, l = t & 63, g = l >> 4, q = l & 15;
  const int rb = blockIdx.x * 16;

  const float* ap = anchor + (size_t)(rb + q) * DIM + wv * 32 + g * 8;
  const f32x4 a0 = *(const f32x4*)ap, a1 = *(const f32x4*)(ap + 4);
  bf16x8 a;
#pragma unroll
  for (int e = 0; e < 4; ++e) {
    a[e] = (short)f32_to_bf16_bits(a0[e]);
    a[4 + e] = (short)f32_to_bf16_bits(a1[e]);
  }

  f32x4 acc[8];
#pragma unroll
  for (int tj = 0; tj < 8; ++tj) acc[tj] = (f32x4){0.f, 0.f, 0.f, 0.f};
#pragma unroll
  for (int tj = 0; tj < 8; ++tj) {
    const bf16x8 b = *(const bf16x8*)(Wtf + (size_t)((tj * 4 + wv) * 64 + l) * 8);
    acc[tj] = __builtin_amdgcn_mfma_f32_16x16x32_bf16(a, b, acc[tj], 0, 0, 0);
  }

#pragma unroll
  for (int tj = 0; tj < 8; ++tj)
#pragma unroll
    for (int r = 0; r < 4; ++r) part[wv][4 * g + r][tj * 16 + q] = acc[tj][r];
  __syncthreads();

  const int row = t >> 4, c = t & 15;
  float v[8];
#pragma unroll
  for (int e = 0; e < 8; ++e) v[e] = bias[c * 8 + e];
#pragma unroll
  for (int s = 0; s < 4; ++s) {
    const f32x4 p0 = *(const f32x4*)&part[s][row][c * 8];
    const f32x4 p1 = *(const f32x4*)&part[s][row][c * 8 + 4];
#pragma unroll
    for (int e = 0; e < 4; ++e) {
      v[e] += p0[e];
      v[4 + e] += p1[e];
    }
  }
  float ss = 0.f;
#pragma unroll
  for (int e = 0; e < 8; ++e) ss += v[e] * v[e];
#pragma unroll
  for (int m = 1; m < 16; m <<= 1) ss += __shfl_xor(ss, m, 64);
  const float inv = ZSCALE / fmaxf(sqrtf(ss), 1e-12f);

  bf16x8 o;
#pragma unroll
  for (int e = 0; e < 8; ++e) o[e] = (short)f32_to_bf16_bits(v[e] * inv);
  const int ks = c >> 2, gg = c & 3;
  *(bf16x8*)(zf + (size_t)(((blockIdx.x * 4 + ks) * 64) + gg * 16 + row) * 8) = o;
}

// ---------- production K2 (identical to R11) ----------
template <int MODE>
__device__ __forceinline__ void simloss_body(
    const unsigned short* __restrict__ zf, float* __restrict__ sumexp,
    float* __restrict__ topacc, float* __restrict__ lds_col, const int r0,
    const int cb, const int t, const int l, const int g, const int q) {
  bf16x8 afr[4][4];
#pragma unroll
  for (int ti = 0; ti < 4; ++ti)
#pragma unroll
    for (int ks = 0; ks < 4; ++ks)
      afr[ti][ks] = *(const bf16x8*)(
          zf + (size_t)((((r0 >> 4) + ti) * 4 + ks) * 512 + l * 8));

  float sums[4][4];
#pragma unroll
  for (int ti = 0; ti < 4; ++ti)
#pragma unroll
    for (int r = 0; r < 4; ++r) sums[ti][r] = 0.f;
  float topv = 0.f;
  const int posr = r0 + 4096;

  bf16x8 ring[4][4];
#define LOADG(slot, gi)                                                 \
  {                                                                     \
    const int bcol = (cb >> 4) + (gi);                                  \
    _Pragma("unroll") for (int ks = 0; ks < 4; ++ks) ring[slot][ks] =   \
        *(const bf16x8*)(zf + (size_t)((bcol * 4 + ks) * 512 + l * 8)); \
  }
#pragma unroll
  for (int s = 0; s < 4; ++s) LOADG(s, s);

#pragma unroll
  for (int k = 0; k < 16; ++k) {
    const int slot = k & 3;
    f32x4 acc[4];
#pragma unroll
    for (int ti = 0; ti < 4; ++ti) acc[ti] = (f32x4){0.f, 0.f, 0.f, 0.f};
#pragma unroll
    for (int ti = 0; ti < 4; ++ti)
#pragma unroll
      for (int ks = 0; ks < 4; ++ks)
        acc[ti] = __builtin_amdgcn_mfma_f32_16x16x32_bf16(
            afr[ti][ks], ring[slot][ks], acc[ti], 0, 0, 0);

    const int c0 = cb + k * 16;
    int dgti = -1, psti = -1;
    if (MODE == 0) {
      const int dgo = c0 - r0;
      dgti = ((unsigned)dgo < 64u) ? (dgo >> 4) : -1;
    }
    if (MODE == 2) {
      const int pso = c0 - posr;
      psti = ((unsigned)pso < 64u) ? (pso >> 4) : -1;
    }
    float cs = 0.f;
#pragma unroll
    for (int ti = 0; ti < 4; ++ti)
#pragma unroll
      for (int r = 0; r < 4; ++r) {
        const float d = acc[ti][r];
        float e = __builtin_amdgcn_exp2f(d);
        if (MODE == 0 && ti == dgti && q == 4 * g + r) e = 0.f;
        if (MODE == 2 && ti == psti && q == 4 * g + r) topv += d;
        sums[ti][r] += e;
        if (MODE != 0) cs += e;
      }
    if (MODE != 0) atomicAdd(&lds_col[k * 16 + q], cs);
    if (k + 4 < 16) LOADG(slot, k + 4);
  }
#undef LOADG

#pragma unroll
  for (int ti = 0; ti < 4; ++ti)
#pragma unroll
    for (int r = 0; r < 4; ++r) {
#pragma unroll
      for (int m = 1; m < 16; m <<= 1)
        sums[ti][r] += __shfl_xor(sums[ti][r], m, 64);
    }
  if (q == 0) {
#pragma unroll
    for (int ti = 0; ti < 4; ++ti)
#pragma unroll
      for (int r = 0; r < 4; ++r)
        atomicAdd(&sumexp[r0 + ti * 16 + 4 * g + r], sums[ti][r]);
  }
  if (MODE != 0) {
    __syncthreads();
    atomicAdd(&sumexp[cb + t], lds_col[t]);
  }
  if (MODE == 2) {
#pragma unroll
    for (int m = 1; m < 64; m <<= 1) topv += __shfl_xor(topv, m, 64);
    if (l == 0) atomicAdd(topacc, 2.f * topv);
  }
}

__global__ __launch_bounds__(256) void k_simloss(
    const unsigned short* __restrict__ zf, float* __restrict__ sumexp,
    float* __restrict__ topacc) {
  __shared__ float lds_col[256];
  const int t = threadIdx.x;
  const int wv = t >> 6, l = t & 63, g = l >> 4, q = l & 15;
  lds_col[t] = 0.f;
  __syncthreads();
  int rem = (int)blockIdx.x, igrp = 0;
  while (rem >= 32 - igrp) { rem -= 32 - igrp; ++igrp; }
  const int jbi = igrp + rem;
  const int r0 = igrp * 256 + wv * 64;
  const int cb = jbi * 256;
  if (igrp == jbi)
    simloss_body<0>(zf, sumexp, topacc, lds_col, r0, cb, t, l, g, q);
  else if (jbi == igrp + 16)
    simloss_body<2>(zf, sumexp, topacc, lds_col, r0, cb, t, l, g, q);
  else
    simloss_body<1>(zf, sumexp, topacc, lds_col, r0, cb, t, l, g, q);
}

// ---------- DIAGNOSTIC ablation kernels (read zf, write dummy only) ----------
// ABL: 0=loads only; 1=+MFMA; 2=+exp2/sums; 3=full MODE1 incl. scatters.
// SMALL: mask footprint to 128KB (L2-hot) to isolate memory-system cost.
template <int ABL, int SMALL, int NIT>
__global__ __launch_bounds__(256) void k_ablate(
    const unsigned short* __restrict__ zf_in, float* __restrict__ dummy) {
  __shared__ float lds_col[256];
  const int t = threadIdx.x;
  const int wv = t >> 6, l = t & 63, g = l >> 4, q = l & 15;
  int rem = (int)blockIdx.x, igrp = 0;
  while (rem >= 32 - igrp) { rem -= 32 - igrp; ++igrp; }
  const int jbi = igrp + rem;
  int r0 = igrp * 256 + wv * 64;
  int cb = jbi * 256;
  if (SMALL) { r0 &= 255; cb &= 255; }  // 16 A-chunks + 16 B-chunks = 128KB hot

#pragma unroll 1
  for (int it = 0; it < NIT; ++it) {
    const unsigned short* zf = opq(zf_in);
    if (ABL >= 3) {
      lds_col[t] = 0.f;
      __syncthreads();
    }
    bf16x8 afr[4][4];
#pragma unroll
    for (int ti = 0; ti < 4; ++ti)
#pragma unroll
      for (int ks = 0; ks < 4; ++ks) {
        afr[ti][ks] = *(const bf16x8*)(
            zf + (size_t)((((r0 >> 4) + ti) * 4 + ks) * 512 + l * 8));
        if (ABL == 0) sinkb(afr[ti][ks]);
      }

    float sums[4][4];
#pragma unroll
    for (int ti = 0; ti < 4; ++ti)
#pragma unroll
      for (int r = 0; r < 4; ++r) sums[ti][r] = 0.f;

    bf16x8 ring[4][4];
#define LOADG(slot, gi)                                                 \
  {                                                                     \
    const int bcol = (cb >> 4) + (gi);                                  \
    _Pragma("unroll") for (int ks = 0; ks < 4; ++ks) ring[slot][ks] =   \
        *(const bf16x8*)(zf + (size_t)((bcol * 4 + ks) * 512 + l * 8)); \
  }
#pragma unroll
    for (int s = 0; s < 4; ++s) LOADG(s, s);

#pragma unroll
    for (int k = 0; k < 16; ++k) {
      const int slot = k & 3;
      if (ABL == 0) {
#pragma unroll
        for (int ks = 0; ks < 4; ++ks) sinkb(ring[slot][ks]);
      } else {
        f32x4 acc[4];
#pragma unroll
        for (int ti = 0; ti < 4; ++ti) acc[ti] = (f32x4){0.f, 0.f, 0.f, 0.f};
#pragma unroll
        for (int ti = 0; ti < 4; ++ti)
#pragma unroll
          for (int ks = 0; ks < 4; ++ks)
            acc[ti] = __builtin_amdgcn_mfma_f32_16x16x32_bf16(
                afr[ti][ks], ring[slot][ks], acc[ti], 0, 0, 0);
        if (ABL == 1) {
#pragma unroll
          for (int ti = 0; ti < 4; ++ti) sinkf(acc[ti][0]);
        } else {
          float cs = 0.f;
#pragma unroll
          for (int ti = 0; ti < 4; ++ti)
#pragma unroll
            for (int r = 0; r < 4; ++r) {
              const float e = __builtin_amdgcn_exp2f(acc[ti][r]);
              sums[ti][r] += e;
              if (ABL >= 3) cs += e;
            }
          if (ABL >= 3) atomicAdd(&lds_col[k * 16 + q], cs);
        }
      }
      if (k + 4 < 16) LOADG(slot, k + 4);
    }
#undef LOADG

    if (ABL == 2) {
#pragma unroll
      for (int ti = 0; ti < 4; ++ti)
#pragma unroll
        for (int r = 0; r < 4; ++r) sinkf(sums[ti][r]);
    }
    if (ABL >= 3) {
#pragma unroll
      for (int ti = 0; ti < 4; ++ti)
#pragma unroll
        for (int r = 0; r < 4; ++r) {
#pragma unroll
          for (int m = 1; m < 16; m <<= 1)
            sums[ti][r] += __shfl_xor(sums[ti][r], m, 64);
        }
      if (q == 0) {
#pragma unroll
        for (int ti = 0; ti < 4; ++ti)
#pragma unroll
          for (int r = 0; r < 4; ++r)
            atomicAdd(&dummy[r0 + ti * 16 + 4 * g + r], sums[ti][r]);
      }
      __syncthreads();
      atomicAdd(&dummy[cb + t], lds_col[t]);
    }
  }
}

// K3: loss = LN2 * (sum_i log2(bottom_i) - topacc) / (b-1)
__global__ __launch_bounds__(1024) void k_final(const float* __restrict__ sumexp,
                                                const float* __restrict__ topacc,
                                                float* __restrict__ out) {
  __shared__ float red[16];
  const int t = threadIdx.x;
  float s = 0.f;
  for (int r = t; r < NROWS; r += 1024) s += __log2f(sumexp[r]);
#pragma unroll
  for (int m = 1; m < 64; m <<= 1) s += __shfl_xor(s, m, 64);
  if ((t & 63) == 0) red[t >> 6] = s;
  __syncthreads();
  if (t == 0) {
    float S1 = 0.f;
#pragma unroll
    for (int i = 0; i < 16; ++i) S1 += red[i];
    out[0] = LN2F * (S1 - topacc[0]) * (1.0f / (float)(NROWS - 1));
  }
}

extern "C" void kernel_launch(void* const* d_in, const int* in_sizes, int n_in,
                              void* d_out, int out_size, void* d_ws, size_t ws_size,
                              hipStream_t stream) {
  const float* anchor = (const float*)d_in[0];
  const float* W = (const float*)d_in[1];
  const float* bias = (const float*)d_in[2];
  float* out = (float*)d_out;

  char* ws = (char*)d_ws;
  unsigned short* zf = (unsigned short*)ws;                        // 2 MB
  float* sumexp = (float*)(ws + (size_t)2 * 1024 * 1024);          // 32 KB
  float* topacc = (float*)(ws + (size_t)2 * 1024 * 1024 + 32768);  // 4 B
  unsigned short* Wtf = (unsigned short*)(ws + (size_t)2 * 1024 * 1024 + 36864);
  float* dummy = (float*)(ws + (size_t)4 * 1024 * 1024);           // diag sink

  // production path (output-exact)
  k_wprep<<<dim3(64), dim3(256), 0, stream>>>(W, Wtf, sumexp, topacc);
  k_proj_norm<<<dim3(NROWS / 16), dim3(256), 0, stream>>>(anchor, Wtf, bias, zf);
  k_simloss<<<dim3(528), dim3(256), 0, stream>>>(zf, sumexp, topacc);
  k_final<<<dim3(1), dim3(1024), 0, stream>>>(sumexp, topacc, out);

  // diagnostics (read zf, write dummy; true cost = dur / NIT)
  k_ablate<0, 0, 24><<<dim3(528), dim3(256), 0, stream>>>(zf, dummy);  // loads, real
  k_ablate<0, 1, 24><<<dim3(528), dim3(256), 0, stream>>>(zf, dummy);  // loads, 128KB
  k_ablate<1, 0, 16><<<dim3(528), dim3(256), 0, stream>>>(zf, dummy);  // +MFMA
  k_ablate<2, 0, 12><<<dim3(528), dim3(256), 0, stream>>>(zf, dummy);  // +exp2/sums
  k_ablate<3, 0, 8><<<dim3(528), dim3(256), 0, stream>>>(zf, dummy);   // full
}

// Round 13
// 42.085 us; speedup vs baseline: 26.3267x; 26.3267x over previous
//
#include <hip/hip_runtime.h>
#include <stdint.h>

typedef short bf16x8 __attribute__((ext_vector_type(8)));
typedef float f32x4 __attribute__((ext_vector_type(4)));

#define NROWS 8192
#define DIM   128
// sqrt(10/ln2): dot of scaled z gives 10*cos/ln2, so exp2(dot)=exp(10*cos)
#define ZSCALE 3.7982824f
#define LN2F  0.6931471805599453f

// zf layout (fragment-linear): chunk (b, ks) = 1KB at (b*4+ks)*1024 bytes;
// lane l (g=l>>4, q=l&15) holds z[b*16+q][ks*32+g*8 .. +8] as bf16x8.
// => A/B fragment loads AND 64-col panel staging are both linear.

__device__ __forceinline__ unsigned short f32_to_bf16_bits(float x) {
  union { float f; uint32_t u; } v; v.f = x;
  uint32_t r = v.u + 0x7FFFu + ((v.u >> 16) & 1u);  // RNE
  return (unsigned short)(r >> 16);
}

#define GLOAD_LDS16(gsrc, ldst)                                      \
  __builtin_amdgcn_global_load_lds(                                  \
      (const __attribute__((address_space(1))) unsigned int*)(gsrc), \
      (__attribute__((address_space(3))) unsigned int*)(ldst), 16, 0, 0)

// K0: Wtf = W in B-fragment order; zero sumexp/topacc.
__global__ __launch_bounds__(256) void k_wprep(const float* __restrict__ W,
                                               unsigned short* __restrict__ Wtf,
                                               float* __restrict__ sumexp,
                                               float* __restrict__ topacc) {
  const int idx = blockIdx.x * 256 + threadIdx.x;  // grid 64 -> 16384
  if (idx < 2048) {
    const int l = idx & 63, chunk = idx >> 6;  // chunk = tj*4+ks
    const int tj = chunk >> 2, ks = chunk & 3, g = l >> 4, q = l & 15;
    const float* wp = W + (size_t)(ks * 32 + g * 8) * DIM + tj * 16 + q;
    bf16x8 o;
#pragma unroll
    for (int e = 0; e < 8; ++e) o[e] = (short)f32_to_bf16_bits(wp[(size_t)e * DIM]);
    *(bf16x8*)(Wtf + (size_t)idx * 8) = o;
  }
  if (idx < NROWS) sumexp[idx] = 0.f;
  if (idx == 0) topacc[0] = 0.f;
}

// K1: zf = fragment-order bf16( ZSCALE * normalize(anchor @ W + bias) ).
// 512 blocks x 4 waves; wave wv computes K-slice ks=wv, LDS reduce,
// normalize + fragment-order store.
__global__ __launch_bounds__(256) void k_proj_norm(
    const float* __restrict__ anchor, const unsigned short* __restrict__ Wtf,
    const float* __restrict__ bias, unsigned short* __restrict__ zf) {
  __shared__ float part[4][16][132];  // padded cols
  const int t = threadIdx.x;
  const int wv = t >> 6, l = t & 63, g = l >> 4, q = l & 15;
  const int rb = blockIdx.x * 16;

  const float* ap = anchor + (size_t)(rb + q) * DIM + wv * 32 + g * 8;
  const f32x4 a0 = *(const f32x4*)ap, a1 = *(const f32x4*)(ap + 4);
  bf16x8 a;
#pragma unroll
  for (int e = 0; e < 4; ++e) {
    a[e] = (short)f32_to_bf16_bits(a0[e]);
    a[4 + e] = (short)f32_to_bf16_bits(a1[e]);
  }

  f32x4 acc[8];
#pragma unroll
  for (int tj = 0; tj < 8; ++tj) acc[tj] = (f32x4){0.f, 0.f, 0.f, 0.f};
#pragma unroll
  for (int tj = 0; tj < 8; ++tj) {
    const bf16x8 b = *(const bf16x8*)(Wtf + (size_t)((tj * 4 + wv) * 64 + l) * 8);
    acc[tj] = __builtin_amdgcn_mfma_f32_16x16x32_bf16(a, b, acc[tj], 0, 0, 0);
  }

#pragma unroll
  for (int tj = 0; tj < 8; ++tj)
#pragma unroll
    for (int r = 0; r < 4; ++r) part[wv][4 * g + r][tj * 16 + q] = acc[tj][r];
  __syncthreads();

  const int row = t >> 4, c = t & 15;  // c = 8-col chunk
  float v[8];
#pragma unroll
  for (int e = 0; e < 8; ++e) v[e] = bias[c * 8 + e];
#pragma unroll
  for (int s = 0; s < 4; ++s) {
    const f32x4 p0 = *(const f32x4*)&part[s][row][c * 8];
    const f32x4 p1 = *(const f32x4*)&part[s][row][c * 8 + 4];
#pragma unroll
    for (int e = 0; e < 4; ++e) {
      v[e] += p0[e];
      v[4 + e] += p1[e];
    }
  }
  float ss = 0.f;
#pragma unroll
  for (int e = 0; e < 8; ++e) ss += v[e] * v[e];
#pragma unroll
  for (int m = 1; m < 16; m <<= 1) ss += __shfl_xor(ss, m, 64);
  const float inv = ZSCALE / fmaxf(sqrtf(ss), 1e-12f);

  bf16x8 o;
#pragma unroll
  for (int e = 0; e < 8; ++e) o[e] = (short)f32_to_bf16_bits(v[e] * inv);
  const int ks = c >> 2, gg = c & 3;
  *(bf16x8*)(zf + (size_t)(((blockIdx.x * 4 + ks) * 64) + gg * 16 + row) * 8) = o;
}

// K2: fused Z @ Z^T -> exp2 -> row sums, m97-style LDS staging.
// Grid 32x32 = 1024 blocks (full matrix); block = 4 waves x 64 i-rows,
// 256-col panel in 4 chunks of 64 cols. Each chunk = 16 CONTIGUOUS KB of zf,
// staged via global_load_lds (no register consumer -> compiler cannot sink
// the loads to their use; they fly across the whole compute phase and drain
// at the barrier, covered by ~3 blocks/CU). B-frags come from LDS ds_read
// (lane-linear, conflict-free). R12 ablation: load-latency exposure was the
// 30-us wall; memory system itself is free.
__global__ __launch_bounds__(256) void k_simloss(
    const unsigned short* __restrict__ zf, float* __restrict__ sumexp,
    float* __restrict__ topacc) {
  __shared__ __align__(16) unsigned short lz[2 * 8192];  // 2 x 16 KB
  const int t = threadIdx.x;
  const int wv = t >> 6, l = t & 63, g = l >> 4, q = l & 15;
  const int igrp = (int)blockIdx.x >> 5, jbi = (int)blockIdx.x & 31;
  const int r0 = igrp * 256 + wv * 64;  // wave's 64 i-rows
  const int cb = jbi * 256;             // block's 256 j-cols
  const int posr = (r0 + 4096) & 8191;  // start of this wave's positive cols

  // A frags: afr[ti][ks] for rows r0+ti*16+q (lane-linear global, 64 VGPR)
  bf16x8 afr[4][4];
#pragma unroll
  for (int ti = 0; ti < 4; ++ti)
#pragma unroll
    for (int ks = 0; ks < 4; ++ks)
      afr[ti][ks] = *(const bf16x8*)(
          zf + (size_t)((((r0 >> 4) + ti) * 4 + ks) * 512 + l * 8));

  float sums[4][4];
#pragma unroll
  for (int ti = 0; ti < 4; ++ti)
#pragma unroll
    for (int r = 0; r < 4; ++r) sums[ti][r] = 0.f;
  float topv = 0.f;

// stage chunk c_ (16 KB = 64 cols x K=128 in fragment order, CONTIGUOUS in
// zf) into LDS half bufsel: 4 gload_lds x 256 threads x 16B. Linear dest.
#define STAGE(bufsel, c_)                                                    \
  _Pragma("unroll") for (int it = 0; it < 4; ++it) {                         \
    const char* src = (const char*)zf +                                      \
                      ((size_t)(jbi * 64 + (c_)*16) << 10) +                 \
                      ((it * 256 + t) << 4);                                 \
    GLOAD_LDS16(src, (char*)lz + (bufsel)*16384 + it * 4096 + wv * 1024);    \
  }

  STAGE(0, 0);
  __syncthreads();  // prologue: buf0 ready

#pragma unroll
  for (int c = 0; c < 4; ++c) {
    // issue next chunk's staging first (fire-and-forget, drains at barrier)
    if (c < 3) STAGE((c + 1) & 1, c + 1);

    const unsigned short* buf = lz + (c & 1) * 8192;
#pragma unroll
    for (int jt = 0; jt < 4; ++jt) {
      // B frags from LDS: lane-linear ds_read_b128, conflict-free
      bf16x8 bfr[4];
#pragma unroll
      for (int ks = 0; ks < 4; ++ks)
        bfr[ks] = *(const bf16x8*)(buf + (size_t)((jt * 4 + ks) * 64 + l) * 8);

      f32x4 acc[4];
#pragma unroll
      for (int ti = 0; ti < 4; ++ti) acc[ti] = (f32x4){0.f, 0.f, 0.f, 0.f};
#pragma unroll
      for (int ti = 0; ti < 4; ++ti)
#pragma unroll
        for (int ks = 0; ks < 4; ++ks)
          acc[ti] = __builtin_amdgcn_mfma_f32_16x16x32_bf16(afr[ti][ks], bfr[ks],
                                                            acc[ti], 0, 0, 0);

      // epilogue for this 64x16 tile: exp2 + diag-skip + pos-capture
      const int c0 = cb + c * 64 + jt * 16;
      const int dgo = c0 - r0, pso = c0 - posr;
      const int dgti = ((unsigned)dgo < 64u) ? (dgo >> 4) : -1;
      const int psti = ((unsigned)pso < 64u) ? (pso >> 4) : -1;
#pragma unroll
      for (int ti = 0; ti < 4; ++ti)
#pragma unroll
        for (int r = 0; r < 4; ++r) {
          const float d = acc[ti][r];
          float e = __builtin_amdgcn_exp2f(d);
          if (ti == dgti && q == 4 * g + r) e = 0.f;    // j == i
          if (ti == psti && q == 4 * g + r) topv += d;  // j == (i+4096)%8192
          sums[ti][r] += e;
        }
    }
    __syncthreads();  // drains staged loads; all reads of buf done
  }
#undef STAGE

  // row-sum reduce across the 16 q-lanes
#pragma unroll
  for (int ti = 0; ti < 4; ++ti)
#pragma unroll
    for (int r = 0; r < 4; ++r) {
#pragma unroll
      for (int m = 1; m < 16; m <<= 1)
        sums[ti][r] += __shfl_xor(sums[ti][r], m, 64);
    }
  if (q == 0) {
#pragma unroll
    for (int ti = 0; ti < 4; ++ti)
#pragma unroll
      for (int r = 0; r < 4; ++r)
        atomicAdd(&sumexp[r0 + ti * 16 + 4 * g + r], sums[ti][r]);
  }

  // top-term: only the block whose j-panel contains this wave's positive cols
  if ((posr & ~255) == cb) {
#pragma unroll
    for (int m = 1; m < 64; m <<= 1) topv += __shfl_xor(topv, m, 64);
    if (l == 0) atomicAdd(topacc, topv);
  }
}

// K3: loss = LN2 * (sum_i log2(bottom_i) - topacc) / (b-1)
__global__ __launch_bounds__(1024) void k_final(const float* __restrict__ sumexp,
                                                const float* __restrict__ topacc,
                                                float* __restrict__ out) {
  __shared__ float red[16];
  const int t = threadIdx.x;
  float s = 0.f;
  for (int r = t; r < NROWS; r += 1024) s += __log2f(sumexp[r]);
#pragma unroll
  for (int m = 1; m < 64; m <<= 1) s += __shfl_xor(s, m, 64);
  if ((t & 63) == 0) red[t >> 6] = s;
  __syncthreads();
  if (t == 0) {
    float S1 = 0.f;
#pragma unroll
    for (int i = 0; i < 16; ++i) S1 += red[i];
    out[0] = LN2F * (S1 - topacc[0]) * (1.0f / (float)(NROWS - 1));
  }
}

extern "C" void kernel_launch(void* const* d_in, const int* in_sizes, int n_in,
                              void* d_out, int out_size, void* d_ws, size_t ws_size,
                              hipStream_t stream) {
  const float* anchor = (const float*)d_in[0];
  const float* W = (const float*)d_in[1];
  const float* bias = (const float*)d_in[2];
  float* out = (float*)d_out;

  char* ws = (char*)d_ws;
  unsigned short* zf = (unsigned short*)ws;                        // 2 MB fragment-order z
  float* sumexp = (float*)(ws + (size_t)2 * 1024 * 1024);          // 32 KB
  float* topacc = (float*)(ws + (size_t)2 * 1024 * 1024 + 32768);  // 4 B
  unsigned short* Wtf = (unsigned short*)(ws + (size_t)2 * 1024 * 1024 + 36864); // 32 KB

  k_wprep<<<dim3(64), dim3(256), 0, stream>>>(W, Wtf, sumexp, topacc);
  k_proj_norm<<<dim3(NROWS / 16), dim3(256), 0, stream>>>(anchor, Wtf, bias, zf);
  k_simloss<<<dim3(32 * 32), dim3(256), 0, stream>>>(zf, sumexp, topacc);
  k_final<<<dim3(1), dim3(1024), 0, stream>>>(sumexp, topacc, out);
}